// Round 1
// baseline (304.623 us; speedup 1.0000x reference)
//
#include <hip/hip_runtime.h>
#include <math.h>

#define NN 4
#define TMAX 20
#define EPS 1e-6f
#define POST_MULT 2.0f

// One block per t. Wave 0 computes the gating coefficients (Sinkhorn on the
// 4x4 in registers via shuffles), then all 256 threads stream x/f_out with
// float4 loads and write y_pre/out. Memory-bound: ~335 MB total traffic.
__global__ __launch_bounds__(256) void fused_mhc_kernel(
    const float* __restrict__ x,          // (T, 4, C)
    const float* __restrict__ f_out,      // (T, C)
    const float* __restrict__ mix,        // (T, 24)
    const float* __restrict__ invr,       // (T,)
    const float* __restrict__ alpha_pre,  // (1,)
    const float* __restrict__ alpha_post, // (1,)
    const float* __restrict__ alpha_res,  // (1,)
    const float* __restrict__ bias,       // (24,)
    float* __restrict__ y_pre,            // (T, C)
    float* __restrict__ out,              // (T, 4, C)
    int C)
{
    const int t = blockIdx.x;
    const int tid = threadIdx.x;

    __shared__ float sh_pre[NN];     // h_pre
    __shared__ float sh_post[NN];    // h_post (already * POST_MULT)
    __shared__ float sh_res[NN * NN];// h_res row-major [j][i]

    if (tid < 64) {
        const int lane = tid;
        const float ir = invr[t];
        if (lane < 16) {
            // lane = i*4 + j  (row i, col j) -- matches reshape(T,4,4) row-major
            float r = mix[t * 24 + 8 + lane] * ir * alpha_res[0] + bias[8 + lane];
            // row max (over j): lanes differing in bits 0,1
            float m = r;
            m = fmaxf(m, __shfl_xor(m, 1));
            m = fmaxf(m, __shfl_xor(m, 2));
            r = __expf(r - m);
            #pragma unroll
            for (int it = 0; it < TMAX; ++it) {
                // row normalize (sum over j)
                float rs = r;
                rs += __shfl_xor(rs, 1);
                rs += __shfl_xor(rs, 2);
                r = r / (rs + EPS);
                // col normalize (sum over i): lanes differing in bits 2,3
                float cs = r;
                cs += __shfl_xor(cs, 4);
                cs += __shfl_xor(cs, 8);
                r = r / (cs + EPS);
            }
            sh_res[lane] = r;
        } else if (lane < 24) {
            const int idx = lane - 16;  // 0..7
            const float a = (idx < NN) ? alpha_pre[0] : alpha_post[0];
            const float z = mix[t * 24 + idx] * ir * a + bias[idx];
            const float sg = 1.0f / (1.0f + __expf(-z));
            if (idx < NN) sh_pre[idx] = sg;
            else          sh_post[idx - NN] = sg * POST_MULT;
        }
    }
    __syncthreads();

    const float hp0 = sh_pre[0], hp1 = sh_pre[1], hp2 = sh_pre[2], hp3 = sh_pre[3];

    const int NV = C >> 2;  // float4 chunks per C-row
    const float4* xv4 = (const float4*)(x + (size_t)t * NN * C);
    const float4* fv4 = (const float4*)(f_out + (size_t)t * C);
    float4* yp4 = (float4*)(y_pre + (size_t)t * C);
    float4* o4  = (float4*)(out + (size_t)t * NN * C);

    for (int v = tid; v < NV; v += blockDim.x) {
        float4 xv[NN];
        #pragma unroll
        for (int n = 0; n < NN; ++n) xv[n] = xv4[n * NV + v];
        const float4 fv = fv4[v];

        // y_pre = sum_n h_pre[n] * x[n]
        float4 yv;
        yv.x = hp0 * xv[0].x; yv.y = hp0 * xv[0].y; yv.z = hp0 * xv[0].z; yv.w = hp0 * xv[0].w;
        yv.x = fmaf(hp1, xv[1].x, yv.x); yv.y = fmaf(hp1, xv[1].y, yv.y);
        yv.z = fmaf(hp1, xv[1].z, yv.z); yv.w = fmaf(hp1, xv[1].w, yv.w);
        yv.x = fmaf(hp2, xv[2].x, yv.x); yv.y = fmaf(hp2, xv[2].y, yv.y);
        yv.z = fmaf(hp2, xv[2].z, yv.z); yv.w = fmaf(hp2, xv[2].w, yv.w);
        yv.x = fmaf(hp3, xv[3].x, yv.x); yv.y = fmaf(hp3, xv[3].y, yv.y);
        yv.z = fmaf(hp3, xv[3].z, yv.z); yv.w = fmaf(hp3, xv[3].w, yv.w);
        yp4[v] = yv;

        // out[j] = sum_i h_res[j][i] * x[i] + h_post[j] * f_out
        #pragma unroll
        for (int j = 0; j < NN; ++j) {
            const float hq = sh_post[j];
            float4 ov;
            ov.x = hq * fv.x; ov.y = hq * fv.y; ov.z = hq * fv.z; ov.w = hq * fv.w;
            #pragma unroll
            for (int i = 0; i < NN; ++i) {
                const float h = sh_res[j * NN + i];
                ov.x = fmaf(h, xv[i].x, ov.x);
                ov.y = fmaf(h, xv[i].y, ov.y);
                ov.z = fmaf(h, xv[i].z, ov.z);
                ov.w = fmaf(h, xv[i].w, ov.w);
            }
            o4[j * NV + v] = ov;
        }
    }
}

extern "C" void kernel_launch(void* const* d_in, const int* in_sizes, int n_in,
                              void* d_out, int out_size, void* d_ws, size_t ws_size,
                              hipStream_t stream) {
    const float* x          = (const float*)d_in[0];
    const float* f_out      = (const float*)d_in[1];
    const float* mix        = (const float*)d_in[2];
    const float* invr       = (const float*)d_in[3];
    const float* alpha_pre  = (const float*)d_in[4];
    const float* alpha_post = (const float*)d_in[5];
    const float* alpha_res  = (const float*)d_in[6];
    const float* bias       = (const float*)d_in[7];

    const int T = in_sizes[3];               // invr is (T,)
    const int C = in_sizes[1] / T;           // f_out is (T, C)

    float* y_pre = (float*)d_out;            // (T, C) first in concat order
    float* out   = (float*)d_out + (size_t)T * C;  // (T, N, C)

    fused_mhc_kernel<<<T, 256, 0, stream>>>(x, f_out, mix, invr,
                                            alpha_pre, alpha_post, alpha_res,
                                            bias, y_pre, out, C);
}

// Round 3
// 304.126 us; speedup vs baseline: 1.0016x; 1.0016x over previous
//
#include <hip/hip_runtime.h>
#include <math.h>

#define NN 4
#define TMAX 20
#define EPS 1e-6f
#define POST_MULT 2.0f

// Native vector type usable with __builtin_nontemporal_store (HIP's float4 is
// a class and is rejected by the builtin).
typedef float vfloat4 __attribute__((ext_vector_type(4)));

// ---------------------------------------------------------------------------
// Kernel 1: compute all per-t coefficients (24 floats per t) into ws.
// 16 lanes per t => 4 t per wave, 16 t per 256-thread block. Fully parallel
// Sinkhorn via intra-16-lane shuffles; no barriers, no LDS.
// ws layout per t: [0..3]=h_pre, [4..7]=h_post*POST_MULT, [8..23]=h_res flat
// (flat = i*4+j, i.e. h_res[i][j]).
// ---------------------------------------------------------------------------
__global__ __launch_bounds__(256) void coeff_kernel(
    const float* __restrict__ mix,        // (T, 24)
    const float* __restrict__ invr,       // (T,)
    const float* __restrict__ alpha_pre,  // (1,)
    const float* __restrict__ alpha_post, // (1,)
    const float* __restrict__ alpha_res,  // (1,)
    const float* __restrict__ bias,       // (24,)
    float* __restrict__ coeffs,           // (T, 24) in ws
    int T)
{
    const int gtid = blockIdx.x * blockDim.x + threadIdx.x;
    const int t    = gtid >> 4;        // one t per 16-lane group
    const int lane = gtid & 15;        // lane within group (= flat index i*4+j)
    if (t >= T) return;

    const float ir = invr[t];

    // --- Sinkhorn on the 4x4 (all 16 lanes participate) ---
    float r = mix[t * 24 + 8 + lane] * ir * alpha_res[0] + bias[8 + lane];
    // row max over j: lanes differing in bits 0,1 (same 16-lane group)
    float m = r;
    m = fmaxf(m, __shfl_xor(m, 1));
    m = fmaxf(m, __shfl_xor(m, 2));
    r = __expf(r - m);
    #pragma unroll
    for (int it = 0; it < TMAX; ++it) {
        float rs = r;                       // row sum (over j)
        rs += __shfl_xor(rs, 1);
        rs += __shfl_xor(rs, 2);
        r = r / (rs + EPS);
        float cs = r;                       // col sum (over i)
        cs += __shfl_xor(cs, 4);
        cs += __shfl_xor(cs, 8);
        r = r / (cs + EPS);
    }
    coeffs[t * 24 + 8 + lane] = r;

    // --- gates: lanes 0..7 additionally compute h_pre / h_post ---
    if (lane < 8) {
        const float a = (lane < NN) ? alpha_pre[0] : alpha_post[0];
        const float z = mix[t * 24 + lane] * ir * a + bias[lane];
        float sg = 1.0f / (1.0f + __expf(-z));
        if (lane >= NN) sg *= POST_MULT;
        coeffs[t * 24 + lane] = sg;
    }
}

// ---------------------------------------------------------------------------
// Kernel 2: pure streaming. One block per t, 256 threads, no LDS, no barrier.
// Coefficient address depends only on blockIdx -> scalar (s_load) loads.
// ---------------------------------------------------------------------------
__global__ __launch_bounds__(256) void stream_kernel(
    const float* __restrict__ x,       // (T, 4, C)
    const float* __restrict__ f_out,   // (T, C)
    const float* __restrict__ coeffs,  // (T, 24)
    float* __restrict__ y_pre,         // (T, C)
    float* __restrict__ out,           // (T, 4, C)
    int C)
{
    const int t   = blockIdx.x;
    const int tid = threadIdx.x;

    const float* cf = coeffs + (size_t)t * 24;
    const float hp0 = cf[0], hp1 = cf[1], hp2 = cf[2], hp3 = cf[3];
    const float hq0 = cf[4], hq1 = cf[5], hq2 = cf[6], hq3 = cf[7];
    float hr[NN][NN];  // hr[j][i] = h_res[j][i] = cf[8 + j*4 + i]
    #pragma unroll
    for (int j = 0; j < NN; ++j)
        #pragma unroll
        for (int i = 0; i < NN; ++i)
            hr[j][i] = cf[8 + j * 4 + i];

    const int NV = C >> 2;
    const vfloat4* xv4 = (const vfloat4*)(x + (size_t)t * NN * C);
    const vfloat4* fv4 = (const vfloat4*)(f_out + (size_t)t * C);
    vfloat4* yp4 = (vfloat4*)(y_pre + (size_t)t * C);
    vfloat4* o4  = (vfloat4*)(out + (size_t)t * NN * C);

    for (int v = tid; v < NV; v += blockDim.x) {
        vfloat4 xv[NN];
        #pragma unroll
        for (int n = 0; n < NN; ++n) xv[n] = xv4[n * NV + v];
        const vfloat4 fv = fv4[v];

        // y_pre = sum_n h_pre[n] * x[n]  (vector ops elementwise on vfloat4)
        vfloat4 yv = hp0 * xv[0] + hp1 * xv[1] + hp2 * xv[2] + hp3 * xv[3];
        __builtin_nontemporal_store(yv, &yp4[v]);

        // out[j] = sum_i hr[j][i] * x[i] + h_post[j] * f_out
        const float hq[NN] = {hq0, hq1, hq2, hq3};
        #pragma unroll
        for (int j = 0; j < NN; ++j) {
            vfloat4 ov = hq[j] * fv;
            #pragma unroll
            for (int i = 0; i < NN; ++i) ov += hr[j][i] * xv[i];
            __builtin_nontemporal_store(ov, &o4[j * NV + v]);
        }
    }
}

extern "C" void kernel_launch(void* const* d_in, const int* in_sizes, int n_in,
                              void* d_out, int out_size, void* d_ws, size_t ws_size,
                              hipStream_t stream) {
    const float* x          = (const float*)d_in[0];
    const float* f_out      = (const float*)d_in[1];
    const float* mix        = (const float*)d_in[2];
    const float* invr       = (const float*)d_in[3];
    const float* alpha_pre  = (const float*)d_in[4];
    const float* alpha_post = (const float*)d_in[5];
    const float* alpha_res  = (const float*)d_in[6];
    const float* bias       = (const float*)d_in[7];

    const int T = in_sizes[3];               // invr is (T,)
    const int C = in_sizes[1] / T;           // f_out is (T, C)

    float* y_pre = (float*)d_out;                   // (T, C)
    float* out   = (float*)d_out + (size_t)T * C;   // (T, N, C)
    float* coeffs = (float*)d_ws;                   // (T, 24)

    const int grid1 = (T * 16 + 255) / 256;
    coeff_kernel<<<grid1, 256, 0, stream>>>(mix, invr, alpha_pre, alpha_post,
                                            alpha_res, bias, coeffs, T);
    stream_kernel<<<T, 256, 0, stream>>>(x, f_out, coeffs, y_pre, out, C);
}